// Round 7
// baseline (589.317 us; speedup 1.0000x reference)
//
#include <hip/hip_runtime.h>
#include <hip/hip_bf16.h>
#include <stdint.h>

#define S_LEN 2048
#define HIDDEN 3584
#define NHEAD 16
#define NKVH 8
#define HDIM 256
#define QKV_N 8192
#define AO_N 4096
#define WINLEN 1024

typedef __attribute__((ext_vector_type(8))) short bf16x8;
typedef __attribute__((ext_vector_type(4))) float f32x4;

__device__ __forceinline__ void async_cp16(const void* g, void* l) {
  __builtin_amdgcn_global_load_lds(
      (const __attribute__((address_space(1))) void*)g,
      (__attribute__((address_space(3))) void*)l, 16, 0, 0);
}

__device__ __forceinline__ float fast_exp2(float x) {
#if __has_builtin(__builtin_amdgcn_exp2f)
  return __builtin_amdgcn_exp2f(x);
#else
  return __exp2f(x);
#endif
}
__device__ __forceinline__ float fast_rcp(float x) {
#if __has_builtin(__builtin_amdgcn_rcpf)
  return __builtin_amdgcn_rcpf(x);
#else
  return 1.0f / x;
#endif
}

__device__ __forceinline__ unsigned short f2bf(float f) {
  unsigned u = __float_as_uint(f);
  u += 0x7FFF + ((u >> 16) & 1);
  return (unsigned short)(u >> 16);
}
__device__ __forceinline__ float bf2f(unsigned short h) {
  return __uint_as_float(((unsigned)h) << 16);
}

// compiler-fenced raw barrier (no vmcnt/lgkmcnt drain inserted)
__device__ __forceinline__ void bar() {
  asm volatile("" ::: "memory");
  __builtin_amdgcn_s_barrier();
  asm volatile("" ::: "memory");
}

// ---------------- elementwise f32 -> bf16 cast (vectorized) ----------------
__global__ void k_cast_bf16(const float* __restrict__ in,
                            unsigned short* __restrict__ out, int n4) {
  int i = blockIdx.x * blockDim.x + threadIdx.x;
  int stride = gridDim.x * blockDim.x;
  for (; i < n4; i += stride) {
    float4 v = ((const float4*)in)[i];
    uint2 o;
    o.x = (unsigned)f2bf(v.x) | ((unsigned)f2bf(v.y) << 16);
    o.y = (unsigned)f2bf(v.z) | ((unsigned)f2bf(v.w) << 16);
    ((uint2*)out)[i] = o;
  }
}

// ------------- transpose + convert: f32 [R][C] -> bf16 [C][R] -------------
__global__ void k_transpose_bf16(const float* __restrict__ in,
                                 unsigned short* __restrict__ out,
                                 int R, int C) {
  __shared__ float tile[64][65];
  int c0 = blockIdx.x * 64, r0 = blockIdx.y * 64;
  int t = threadIdx.x;
#pragma unroll
  for (int j = 0; j < 16; ++j) {
    int idx = t + j * 256;
    int rl = idx >> 6, cl = idx & 63;
    tile[rl][cl] = in[(size_t)(r0 + rl) * C + c0 + cl];
  }
  __syncthreads();
#pragma unroll
  for (int j = 0; j < 16; ++j) {
    int idx = t + j * 256;
    int cl = idx >> 6, rl = idx & 63;
    out[(size_t)(c0 + cl) * R + r0 + rl] = f2bf(tile[rl][cl]);
  }
}

// ---- bf16 GEMM, phase-split + counted-vmcnt schedule (T3+T4+T5+T1+T2) ----
// C[M][N] = A[M][K] * B^T (B stored [N][K]).  BN=256, BK=64, 8 waves (2x4).
// Double-buffered K-tiles; next tile's global_load_lds issued at iteration
// top, waited with counted vmcnt (never 0 in main loop); 4 phases per K-tile,
// each {ds_read frag subtile -> setprio(1) -> MFMA quadrant -> setprio(0) ->
// s_barrier}. Raw s_barrier + asm waits: compiler cannot insert vmcnt(0)
// drains. XOR-swizzled LDS via pre-swizzled source (0 bank conflicts).
template <int BM, bool OUT_BF16>
__global__ __launch_bounds__(512, 1) void k_gemm2(
    const unsigned short* __restrict__ A, const unsigned short* __restrict__ B,
    void* __restrict__ Cout, int M, int N, int K) {
  constexpr int M_REP = BM / 32;   // m-fragments per wave (8 or 4)
  constexpr int HM = M_REP / 2;    // m-fragments per phase-half (4 or 2)
  constexpr int LPK = BM / 64 + 4; // global_load_lds per thread per K-tile
  __shared__ unsigned short sA[2][BM * 64];
  __shared__ unsigned short sB[2][256 * 64];
  const int t = threadIdx.x;
  const int lane = t & 63;
  const int wid = t >> 6;
  const int wr = wid >> 2, wc = wid & 3;  // 2 x 4 waves
  const int lrow = lane & 15, lgrp = lane >> 4;

  // XCD-bijective block swizzle (nwg % 8 == 0 for both call sites)
  const int gx = gridDim.x;
  const int nwg = gx * gridDim.y;
  const int bid = blockIdx.y * gx + blockIdx.x;
  const int swz = (bid & 7) * (nwg >> 3) + (bid >> 3);
  const int m0 = (swz / gx) * BM;
  const int n0 = (swz % gx) * 256;

  const int NT = K >> 6;

  // staging: thread -> row r = t>>3 within 64-row group, chunk c = t&7 of
  // 8 x 16B per 128B row; source chunk pre-swizzled so LDS[r][c] holds
  // global chunk c ^ (r&7).
  const int sr = t >> 3;
  const int scs = ((t & 7) ^ (sr & 7)) * 8;  // source chunk (elems)
  auto stage = [&](int kt, int buf) {
    const size_t kb = (size_t)kt * 64;
    unsigned short* dA = &sA[buf][sr * 64 + (t & 7) * 8];
    unsigned short* dB = &sB[buf][sr * 64 + (t & 7) * 8];
#pragma unroll
    for (int l = 0; l < BM / 64; ++l)
      async_cp16(A + (size_t)(m0 + l * 64 + sr) * K + kb + scs,
                 dA + l * 64 * 64);
#pragma unroll
    for (int l = 0; l < 4; ++l)
      async_cp16(B + (size_t)(n0 + l * 64 + sr) * K + kb + scs,
                 dB + l * 64 * 64);
  };

  f32x4 acc[M_REP][4] = {};

  stage(0, 0);
  for (int kt = 0; kt < NT; ++kt) {
    const int buf = kt & 1;
    if (kt + 1 < NT) {
      // issue next K-tile (other buffer: its readers finished at the trailing
      // barrier of iteration kt-1), then counted wait: only kt's loads must
      // land; kt+1's stay in flight across this whole K-tile's compute.
      stage(kt + 1, buf ^ 1);
      if constexpr (LPK == 8)
        asm volatile("s_waitcnt vmcnt(8)" ::: "memory");
      else
        asm volatile("s_waitcnt vmcnt(6)" ::: "memory");
    } else {
      asm volatile("s_waitcnt vmcnt(0)" ::: "memory");
    }
    bar();  // all waves' staged data visible before any ds_read

    const unsigned short* a = sA[buf];
    const unsigned short* b = sB[buf];
    auto ldA = [&](int mf, int kk) {
      return *(const bf16x8*)&a[(wr * (BM / 2) + mf * 16 + lrow) * 64 +
                                (((kk * 4 + lgrp)) ^ (lrow & 7)) * 8];
    };
    auto ldB = [&](int nf, int kk) {
      return *(const bf16x8*)&b[(wc * 64 + nf * 16 + lrow) * 64 +
                                (((kk * 4 + lgrp)) ^ (lrow & 7)) * 8];
    };

    bf16x8 aA[HM][2], bB0[2][2], bB1[2][2];
    // ---- phase 0: read A-half0 + B-half0, MFMA quadrant (0,0) ----
#pragma unroll
    for (int i = 0; i < HM; ++i) {
      aA[i][0] = ldA(i, 0);
      aA[i][1] = ldA(i, 1);
    }
#pragma unroll
    for (int j = 0; j < 2; ++j) {
      bB0[j][0] = ldB(j, 0);
      bB0[j][1] = ldB(j, 1);
    }
    __builtin_amdgcn_s_setprio(1);
#pragma unroll
    for (int i = 0; i < HM; ++i)
#pragma unroll
      for (int j = 0; j < 2; ++j)
#pragma unroll
        for (int kk = 0; kk < 2; ++kk)
          acc[i][j] = __builtin_amdgcn_mfma_f32_16x16x32_bf16(
              aA[i][kk], bB0[j][kk], acc[i][j], 0, 0, 0);
    __builtin_amdgcn_s_setprio(0);
    bar();
    // ---- phase 1: read B-half1, MFMA quadrant (0,1) ----
#pragma unroll
    for (int j = 0; j < 2; ++j) {
      bB1[j][0] = ldB(2 + j, 0);
      bB1[j][1] = ldB(2 + j, 1);
    }
    __builtin_amdgcn_s_setprio(1);
#pragma unroll
    for (int i = 0; i < HM; ++i)
#pragma unroll
      for (int j = 0; j < 2; ++j)
#pragma unroll
        for (int kk = 0; kk < 2; ++kk)
          acc[i][2 + j] = __builtin_amdgcn_mfma_f32_16x16x32_bf16(
              aA[i][kk], bB1[j][kk], acc[i][2 + j], 0, 0, 0);
    __builtin_amdgcn_s_setprio(0);
    bar();
    // ---- phase 2: read A-half1 (reuse regs), MFMA quadrant (1,1) ----
#pragma unroll
    for (int i = 0; i < HM; ++i) {
      aA[i][0] = ldA(HM + i, 0);
      aA[i][1] = ldA(HM + i, 1);
    }
    __builtin_amdgcn_s_setprio(1);
#pragma unroll
    for (int i = 0; i < HM; ++i)
#pragma unroll
      for (int j = 0; j < 2; ++j)
#pragma unroll
        for (int kk = 0; kk < 2; ++kk)
          acc[HM + i][2 + j] = __builtin_amdgcn_mfma_f32_16x16x32_bf16(
              aA[i][kk], bB1[j][kk], acc[HM + i][2 + j], 0, 0, 0);
    __builtin_amdgcn_s_setprio(0);
    bar();
    // ---- phase 3: MFMA quadrant (1,0) (no reads) ----
    __builtin_amdgcn_s_setprio(1);
#pragma unroll
    for (int i = 0; i < HM; ++i)
#pragma unroll
      for (int j = 0; j < 2; ++j)
#pragma unroll
        for (int kk = 0; kk < 2; ++kk)
          acc[HM + i][j] = __builtin_amdgcn_mfma_f32_16x16x32_bf16(
              aA[i][kk], bB0[j][kk], acc[HM + i][j], 0, 0, 0);
    __builtin_amdgcn_s_setprio(0);
    bar();  // trailing: protects next iteration's stage-issue (WAR)
  }

#pragma unroll
  for (int mf = 0; mf < M_REP; ++mf) {
    int row_b = m0 + wr * (BM / 2) + mf * 16 + lgrp * 4;
#pragma unroll
    for (int nf = 0; nf < 4; ++nf) {
      int col = n0 + wc * 64 + nf * 16 + lrow;
#pragma unroll
      for (int r = 0; r < 4; ++r) {
        int row = row_b + r;
        if constexpr (OUT_BF16)
          ((unsigned short*)Cout)[(size_t)row * N + col] = f2bf(acc[mf][nf][r]);
        else
          ((float*)Cout)[(size_t)row * N + col] = acc[mf][nf][r];
      }
    }
  }
}

// ---------------- RoPE + layout: qkv[2048][8192] -> Q, K (roped), VTblk ----
// VTblk layout: [kvh][k/64][256 d][64 k]  (each 64-key V^T tile contiguous)
__global__ void k_rope_layout(const unsigned short* __restrict__ qkv,
                              const float* __restrict__ fcos,
                              const float* __restrict__ fsin,
                              unsigned short* __restrict__ Q,
                              unsigned short* __restrict__ K,
                              unsigned short* __restrict__ VT) {
  int s0 = blockIdx.x * 64;
  int y = blockIdx.y;
  int t = threadIdx.x;
  if (y < 24) {
    int colb = (y < 16) ? y * 256 : 4096 + (y - 16) * 256;
    unsigned short* out =
        (y < 16) ? (Q + (size_t)y * S_LEN * HDIM)
                 : (K + (size_t)(y - 16) * S_LEN * HDIM);
#pragma unroll 4
    for (int j = 0; j < 32; ++j) {
      int idx = t + j * 256;
      int sl = idx >> 7;
      int d = idx & 127;
      int s = s0 + sl;
      float x1 = bf2f(qkv[(size_t)s * QKV_N + colb + d]);
      float x2 = bf2f(qkv[(size_t)s * QKV_N + colb + d + 128]);
      float c = fcos[s * 128 + d], sn = fsin[s * 128 + d];
      out[(size_t)s * HDIM + d] = f2bf(x1 * c - x2 * sn);
      out[(size_t)s * HDIM + d + 128] = f2bf(x1 * sn + x2 * c);
    }
  } else {
    int kh = y - 24;
    __shared__ unsigned short tile[64][258];
#pragma unroll 4
    for (int j = 0; j < 64; ++j) {
      int idx = t + j * 256;
      int sl = idx >> 8;
      int d = idx & 255;
      tile[sl][d] = qkv[(size_t)(s0 + sl) * QKV_N + 6144 + kh * 256 + d];
    }
    __syncthreads();
    size_t base = (size_t)kh * HDIM * S_LEN + (size_t)(s0 >> 6) * (HDIM * 64);
#pragma unroll 4
    for (int j = 0; j < 64; ++j) {
      int idx = t + j * 256;
      int d = idx >> 6;
      int sl = idx & 63;
      VT[base + idx] = tile[sl][d];
    }
  }
}

// ---------------- windowed softcap attention (LDS-staged, cooperative) ------
__global__ __launch_bounds__(256, 2) void k_attn(
    const unsigned short* __restrict__ Q,    // [16][2048][256]
    const unsigned short* __restrict__ K,    // [8][2048][256]
    const unsigned short* __restrict__ VTB,  // [8][32][256][64] blocked V^T
    unsigned short* __restrict__ O) {        // [2048][4096]
  __shared__ unsigned short sK[64 * 256];    // 32 KB
  __shared__ unsigned short sV[256 * 64];    // 32 KB
  __shared__ unsigned short sP[4][16 * 64];  // 8 KB (per-wave P tiles)
  const int t = threadIdx.x, lane = t & 63, w = t >> 6;
  const int h = blockIdx.y;
  const int r0b = blockIdx.x * 64;
  const int r0w = r0b + w * 16;
  const int lrow = lane & 15, lgrp = lane >> 4;
  const unsigned short* Qh = Q + (size_t)h * S_LEN * HDIM;
  const char* KhB = (const char*)(K + (size_t)(h >> 1) * S_LEN * HDIM);
  const char* VbB = (const char*)(VTB + (size_t)(h >> 1) * S_LEN * HDIM);

  const int cK = t & 31;
  const int rK = t >> 5;
  const int csK = (cK & 24) | ((cK ^ rK) & 7);
  const int ksrcoff = rK * 512 + csK * 16;
  const int csV = (t & 7) ^ ((t >> 3) & 7);
  const int vsrcoff = (t >> 3) * 128 + csV * 16;

  bf16x8 qf[8];
#pragma unroll
  for (int dc = 0; dc < 8; ++dc)
    qf[dc] =
        *(const bf16x8*)&Qh[(size_t)(r0w + lrow) * HDIM + dc * 32 + lgrp * 8];

  f32x4 zero4 = {0.f, 0.f, 0.f, 0.f};
  f32x4 o[16];
#pragma unroll
  for (int i = 0; i < 16; ++i) o[i] = zero4;
  float psum[4] = {0.f, 0.f, 0.f, 0.f};

  const int klo = (r0b >= 1024) ? (r0b - 1024) : 0;
  const int nsteps = ((r0b - klo) >> 6) + 1;

  const float c_pre = 0.0625f / 50.0f;
  const float c_2l2e = 2.8853900817779268f;
  const float c_l2e = 1.4426950408889634f;
  unsigned short* myP = sP[w];

  for (int step = 0; step < nsteps; ++step) {
    const int k0 = klo + step * 64;
    __syncthreads();
    {
      const char* ks = KhB + (size_t)k0 * 512;
      const char* vs = VbB + (size_t)(k0 >> 6) * 32768;
      char* dK = (char*)sK + t * 16;
      char* dV = (char*)sV + t * 16;
#pragma unroll
      for (int rr = 0; rr < 8; ++rr)
        async_cp16(ks + ksrcoff + rr * 4096, dK + rr * 4096);
#pragma unroll
      for (int rr = 0; rr < 8; ++rr)
        async_cp16(vs + vsrcoff + rr * 4096, dV + rr * 4096);
    }
    __syncthreads();

#pragma unroll
    for (int st = 0; st < 4; ++st) {
      const int row = st * 16 + lrow;
      const int rs7 = lrow & 7;
      f32x4 sa = zero4, sb = zero4;
#pragma unroll
      for (int dc = 0; dc < 4; ++dc) {
        const int La = dc * 4 + lgrp;
        const int Lb = (dc + 4) * 4 + lgrp;
        bf16x8 kfa = *(const bf16x8*)&sK[row * 256 +
                                         ((La & 24) | ((La ^ rs7) & 7)) * 8];
        bf16x8 kfb = *(const bf16x8*)&sK[row * 256 +
                                         ((Lb & 24) | ((Lb ^ rs7) & 7)) * 8];
        sa = __builtin_amdgcn_mfma_f32_16x16x32_bf16(qf[dc], kfa, sa, 0, 0, 0);
        sb = __builtin_amdgcn_mfma_f32_16x16x32_bf16(qf[dc + 4], kfb, sb, 0, 0,
                                                     0);
      }
      f32x4 s = sa + sb;
#pragma unroll
      for (int r = 0; r < 4; ++r) {
        const int q = r0w + lgrp * 4 + r;
        const int k = k0 + st * 16 + lrow;
        float tt = s[r] * c_pre;
        tt = fminf(fmaxf(tt, -10.f), 10.f);
        float z = fast_exp2(tt * c_2l2e);
        float sc = (z - 1.f) * fast_rcp(z + 1.f) * 50.f;
        float p = 0.f;
        if (k <= q && (q - k) < WINLEN)
          p = fast_exp2((sc - 50.f) * c_l2e);
        unsigned short pb = f2bf(p);
        psum[r] += bf2f(pb);
        const int qrow = lgrp * 4 + r;
        const int cc = st * 2 + (lrow >> 3);
        myP[qrow * 64 + (cc ^ (qrow & 7)) * 8 + (lrow & 7)] = pb;
      }
    }

#pragma unroll
    for (int ks2 = 0; ks2 < 2; ++ks2) {
      const int cc = ks2 * 4 + lgrp;
      bf16x8 pf = *(const bf16x8*)&myP[lrow * 64 + (cc ^ (lrow & 7)) * 8];
#pragma unroll
      for (int dt = 0; dt < 16; ++dt) {
        const int d = dt * 16 + lrow;
        bf16x8 vf = *(const bf16x8*)&sV[d * 64 + (cc ^ (lrow & 7)) * 8];
        o[dt] = __builtin_amdgcn_mfma_f32_16x16x32_bf16(pf, vf, o[dt], 0, 0, 0);
      }
    }
  }

#pragma unroll
  for (int r = 0; r < 4; ++r) {
    float v = psum[r];
    v += __shfl_xor(v, 1);
    v += __shfl_xor(v, 2);
    v += __shfl_xor(v, 4);
    v += __shfl_xor(v, 8);
    psum[r] = 1.0f / v;
  }
#pragma unroll
  for (int dt = 0; dt < 16; ++dt)
#pragma unroll
    for (int r = 0; r < 4; ++r) {
      int row = r0w + lgrp * 4 + r;
      O[(size_t)row * AO_N + h * HDIM + dt * 16 + lrow] =
          f2bf(o[dt][r] * psum[r]);
    }
}

extern "C" void kernel_launch(void* const* d_in, const int* in_sizes, int n_in,
                              void* d_out, int out_size, void* d_ws,
                              size_t ws_size, hipStream_t stream) {
  const float* hidden = (const float*)d_in[0];
  const float* Wqkv = (const float*)d_in[1];
  const float* Wo = (const float*)d_in[2];
  const float* fcos = (const float*)d_in[3];
  const float* fsin = (const float*)d_in[4];
  float* out = (float*)d_out;
  char* ws = (char*)d_ws;

  unsigned short* WqkvT = (unsigned short*)(ws + 0);
  unsigned short* hb = (unsigned short*)(ws + 58720256);
  unsigned short* qkv = (unsigned short*)(ws + 73400320);
  unsigned short* WoT = (unsigned short*)(ws + 106954752);
  unsigned short* Qb = WqkvT;                            // [16][2048][256]
  unsigned short* Kb = WqkvT + (size_t)16 * 2048 * 256;  // [8][2048][256]
  unsigned short* VTb = WqkvT + (size_t)24 * 2048 * 256; // [8][32][256][64]
  unsigned short* AO = qkv;                              // [2048][4096]

  k_cast_bf16<<<1024, 256, 0, stream>>>(hidden, hb, (2048 * 3584) / 4);
  k_transpose_bf16<<<dim3(8192 / 64, 3584 / 64), 256, 0, stream>>>(
      Wqkv, WqkvT, 3584, 8192);
  k_transpose_bf16<<<dim3(3584 / 64, 4096 / 64), 256, 0, stream>>>(
      Wo, WoT, 4096, 3584);
  k_gemm2<256, true><<<dim3(8192 / 256, 2048 / 256), 512, 0, stream>>>(
      hb, WqkvT, qkv, 2048, 8192, 3584);
  k_rope_layout<<<dim3(32, 32), 256, 0, stream>>>(qkv, fcos, fsin, Qb, Kb, VTb);
  k_attn<<<dim3(32, 16), 256, 0, stream>>>(Qb, Kb, VTb, AO);
  k_gemm2<128, false><<<dim3(3584 / 256, 2048 / 128), 512, 0, stream>>>(
      AO, WoT, out, 2048, 3584, 4096);
}